// Round 7
// baseline (772.260 us; speedup 1.0000x reference)
//
#include <hip/hip_runtime.h>
#include <hip/hip_cooperative_groups.h>

namespace cg = cooperative_groups;

// TensorProductConv, round 7: single cooperative kernel, 4 phases with
// grid.sync() between them (kills 3 dispatch boundaries + memset dispatch):
//   P0 zero counters -> P1 histogram+bucket(edge,col) -> P2 one-wave-per-row
//   register accumulation (chunked rows/wave, next-row prefetch) -> P3 rare
//   overflow fallback. MAXDEG shrunk 64->32 (overflow path covers the
//   Poisson tail), halving bucket read traffic.
//
// X: (V, 4*C) f32, Y: (E, 4) f32, W: (E, 5*C) f32, rows/cols: (E,) int32.
// Z: (V, 11*C) f32.  C = 32, V = 50000, E = 800000 (avg degree 16).

#define C 32
#define ZCOLS (11 * C)
#define MAXDEG 32          // Poisson(16): P(deg > 32) ~ 1.5e-4/row; overflow list covers the tail
#define OVF_MAX 65536
#define INV_SQRT3 0.57735026918962576451f
#define INV_SQRT2 0.70710678118654752440f

struct alignas(8) EdgeCol { int e; int c; };

__global__ void __launch_bounds__(256, 4)
tpconv_fused(const float* __restrict__ X,
             const float* __restrict__ Y,
             const float* __restrict__ W,
             const int* __restrict__ rows,
             const int* __restrict__ cols,
             float* __restrict__ Z,
             int* __restrict__ cnt,        // V+1 ints; cnt[V] = overflow count
             EdgeCol* __restrict__ bucket, // V * MAXDEG pairs
             int* __restrict__ ovf_list,   // OVF_MAX ints
             int V, int E) {
    cg::grid_group grid = cg::this_grid();
    const int tid = blockIdx.x * blockDim.x + threadIdx.x;
    const int nth = gridDim.x * blockDim.x;

    // ---------------- P0: zero counters ----------------
    for (int i = tid; i < V + 1; i += nth) cnt[i] = 0;
    grid.sync();

    // ---------------- P1: histogram + (edge,col) bucket scatter ----------------
    int* ovf_cnt = cnt + V;
    for (int e = tid; e < E; e += nth) {
        const int r = rows[e];
        const int k = atomicAdd(&cnt[r], 1);
        if (k < MAXDEG) {
            EdgeCol p; p.e = e; p.c = cols[e];
            bucket[(size_t)r * MAXDEG + k] = p;
        } else {
            const int o = atomicAdd(ovf_cnt, 1);
            if (o < OVF_MAX) ovf_list[o] = e;
        }
    }
    __threadfence();
    grid.sync();

    // ---------------- P2: one wave per row, register accumulation ----------------
    {
        const int nwaves = nth >> 6;
        const int wave   = tid >> 6;
        const int lane   = threadIdx.x & 63;
        const int c = lane & 31;   // channel owned by this lane
        const int h = lane >> 5;   // half-wave: h=0 even edges, h=1 odd edges
        const int rpw = (V + nwaves - 1) / nwaves;   // rows per wave (chunked)
        const int r0 = wave * rpw;
        const int r1 = (r0 + rpw < V) ? (r0 + rpw) : V;

        if (r0 < V) {
            // prologue: two independent loads for the first row
            int n_cur = cnt[r0];
            EdgeCol p_cur; p_cur.e = 0; p_cur.c = 0;
            if (lane < MAXDEG) p_cur = bucket[(size_t)r0 * MAXDEG + lane];

            for (int row = r0; row < r1; ++row) {
                // prefetch next row's (cnt, pairs) while crunching this one
                int n_nxt = 0;
                EdgeCol p_nxt; p_nxt.e = 0; p_nxt.c = 0;
                if (row + 1 < r1) {
                    n_nxt = cnt[row + 1];
                    if (lane < MAXDEG) p_nxt = bucket[(size_t)(row + 1) * MAXDEG + lane];
                }

                int n = n_cur;
                if (n > MAXDEG) n = MAXDEG;
                const int eb = p_cur.e;
                const int cb = p_cur.c;

                float acc[11];
#pragma unroll
                for (int j = 0; j < 11; ++j) acc[j] = 0.0f;

                auto body = [&](int e, int col) {
                    const float4 y = *reinterpret_cast<const float4*>(Y + (size_t)e * 4);

                    const float* Xe = X + (size_t)col * (4 * C);
                    const float xj0 = Xe[c];
                    const float a0  = Xe[C + 3 * c + 0];
                    const float a1  = Xe[C + 3 * c + 1];
                    const float a2  = Xe[C + 3 * c + 2];

                    const float* We = W + (size_t)e * (5 * C);
                    const float w0 = We[0 * C + c];
                    const float w1 = We[1 * C + c];
                    const float w2 = We[2 * C + c];
                    const float w3 = We[3 * C + c];
                    const float w4 = We[4 * C + c];

                    acc[0] += w0 * xj0 * y.x;

                    const float t01 = w1 * xj0;
                    acc[1] += t01 * y.y;
                    acc[2] += t01 * y.z;
                    acc[3] += t01 * y.w;

                    const float t10 = w2 * y.x;
                    acc[4] += t10 * a0;
                    acc[5] += t10 * a1;
                    acc[6] += t10 * a2;

                    acc[7] += w3 * (a0 * y.y + a1 * y.z + a2 * y.w) * INV_SQRT3;

                    const float s = w4 * INV_SQRT2;
                    acc[8]  += s * (a1 * y.w - a2 * y.z);
                    acc[9]  += s * (a2 * y.y - a0 * y.w);
                    acc[10] += s * (a0 * y.z - a1 * y.y);
                };

                // wave-uniform trip count; shfls issue fully converged.
                // half-wave h handles indices h, h+2, ... (unroll-by-2).
                // max shfl index 4*jmax-1 <= 31 for n <= 32.
                const int jmax = (n + 3) >> 2;
                for (int j = 0; j < jmax; ++j) {
                    const int ia = 4 * j + h;
                    const int ib = ia + 2;
                    const int ea = __shfl(eb, ia), ca = __shfl(cb, ia);
                    const int e2 = __shfl(eb, ib), c2 = __shfl(cb, ib);
                    if (ia < n) body(ea, ca);
                    if (ib < n) body(e2, c2);
                }

                // combine the two half-wave partial sums (converged here)
#pragma unroll
                for (int j = 0; j < 11; ++j) acc[j] += __shfl_xor(acc[j], 32);

                if (h == 0) {
                    float* Zr = Z + (size_t)row * ZCOLS;
                    Zr[c]                 = acc[0];
                    Zr[C + 3 * c + 0]     = acc[1];
                    Zr[C + 3 * c + 1]     = acc[2];
                    Zr[C + 3 * c + 2]     = acc[3];
                    Zr[4 * C + 3 * c + 0] = acc[4];
                    Zr[4 * C + 3 * c + 1] = acc[5];
                    Zr[4 * C + 3 * c + 2] = acc[6];
                    Zr[7 * C + c]         = acc[7];
                    Zr[8 * C + 3 * c + 0] = acc[8];
                    Zr[8 * C + 3 * c + 1] = acc[9];
                    Zr[8 * C + 3 * c + 2] = acc[10];
                }

                n_cur = n_nxt;
                p_cur = p_nxt;
            }
        }
    }
    __threadfence();
    grid.sync();

    // ---------------- P3: rare-overflow fallback (normally ~0 edges) ----------------
    {
        int no = *ovf_cnt;
        if (no > OVF_MAX) no = OVF_MAX;
        const int total = no * C;
        for (int t = tid; t < total; t += nth) {
            const int i = t >> 5, c = t & 31;
            const int e = ovf_list[i];
            const float4 y = *reinterpret_cast<const float4*>(Y + (size_t)e * 4);
            const int row = rows[e];
            const int col = cols[e];
            const float* Xe = X + (size_t)col * (4 * C);
            const float xj0 = Xe[c];
            const float a0  = Xe[C + 3 * c + 0];
            const float a1  = Xe[C + 3 * c + 1];
            const float a2  = Xe[C + 3 * c + 2];
            const float* We = W + (size_t)e * (5 * C);
            const float w0 = We[c], w1 = We[C + c], w2 = We[2 * C + c],
                        w3 = We[3 * C + c], w4 = We[4 * C + c];
            float* Zr = Z + (size_t)row * ZCOLS;
            atomicAdd(&Zr[c], w0 * xj0 * y.x);
            const float t01 = w1 * xj0;
            atomicAdd(&Zr[C + 3 * c + 0], t01 * y.y);
            atomicAdd(&Zr[C + 3 * c + 1], t01 * y.z);
            atomicAdd(&Zr[C + 3 * c + 2], t01 * y.w);
            const float t10 = w2 * y.x;
            atomicAdd(&Zr[4 * C + 3 * c + 0], t10 * a0);
            atomicAdd(&Zr[4 * C + 3 * c + 1], t10 * a1);
            atomicAdd(&Zr[4 * C + 3 * c + 2], t10 * a2);
            atomicAdd(&Zr[7 * C + c], w3 * (a0 * y.y + a1 * y.z + a2 * y.w) * INV_SQRT3);
            const float s = w4 * INV_SQRT2;
            atomicAdd(&Zr[8 * C + 3 * c + 0], s * (a1 * y.w - a2 * y.z));
            atomicAdd(&Zr[8 * C + 3 * c + 1], s * (a2 * y.y - a0 * y.w));
            atomicAdd(&Zr[8 * C + 3 * c + 2], s * (a0 * y.z - a1 * y.y));
        }
    }
}

extern "C" void kernel_launch(void* const* d_in, const int* in_sizes, int n_in,
                              void* d_out, int out_size, void* d_ws, size_t ws_size,
                              hipStream_t stream) {
    const float* X    = (const float*)d_in[0];
    const float* Y    = (const float*)d_in[1];
    const float* W    = (const float*)d_in[2];
    const int*   rows = (const int*)d_in[3];
    const int*   cols = (const int*)d_in[4];
    float*       Z    = (float*)d_out;

    int E = in_sizes[1] / 4;        // Y is (E, 4)
    int V = in_sizes[0] / (4 * C);  // X is (V, 4*C)

    // workspace layout: [bucket: V*MAXDEG EdgeCol (8B, at offset 0)]
    //                   [cnt: V+1 ints][ovf_list: OVF_MAX ints]
    EdgeCol* bucket   = (EdgeCol*)d_ws;
    int*     cnt      = (int*)(bucket + (size_t)V * MAXDEG);
    int*     ovf_list = cnt + (V + 1);

    // co-resident grid sizing for the cooperative launch
    int perCU = 0;
    hipError_t oerr = hipOccupancyMaxActiveBlocksPerMultiprocessor(
        &perCU, (const void*)tpconv_fused, 256, 0);
    if (oerr != hipSuccess || perCU < 1) perCU = 2;   // conservative fallback
    if (perCU > 8) perCU = 8;
    int numCU = 256;                                   // MI355X; query as backup
    hipDeviceProp_t props;
    if (hipGetDeviceProperties(&props, 0) == hipSuccess && props.multiProcessorCount > 0)
        numCU = props.multiProcessorCount;
    int nblocks = perCU * numCU;

    void* args[] = {(void*)&X, (void*)&Y, (void*)&W, (void*)&rows, (void*)&cols,
                    (void*)&Z, (void*)&cnt, (void*)&bucket, (void*)&ovf_list,
                    (void*)&V, (void*)&E};
    hipLaunchCooperativeKernel((const void*)tpconv_fused,
                               dim3(nblocks), dim3(256), args, 0, stream);
}

// Round 8
// 234.299 us; speedup vs baseline: 3.2960x; 3.2960x over previous
//
#include <hip/hip_runtime.h>
#include <hip/hip_bf16.h>

// TensorProductConv, round 8: back to the proven 3-kernel structure (R6),
// with bucket slimmed to 4-byte entries and MAXDEG 32:
//   - bucket region 25.6 MB -> 6.4 MB: halves phase-1 scattered write
//     amplification, keeps bucket L2/L3-resident for phase-2 prologue.
//   - cols[e] re-gathered in the body (R4 A/B proved preloading cols is
//     perf-neutral, so dropping it from the bucket is free).
//   - 2048 blocks = 8192 persistent waves (full CU residency), strided row
//     assignment (neighboring waves read neighboring bucket rows).
// R7 lesson: do NOT fuse into a cooperative kernel (32-VGPR codegen killed
// MLP -> 0.5 TB/s). Keep separate dispatches.
//
// X: (V, 4*C) f32, Y: (E, 4) f32, W: (E, 5*C) f32, rows/cols: (E,) int32.
// Z: (V, 11*C) f32.  C = 32, V = 50000, E = 800000 (avg degree 16).

#define C 32
#define ZCOLS (11 * C)
#define MAXDEG 32          // Poisson(16): ~35 edges total overflow; ovf path covers them
#define OVF_MAX 65536
#define INV_SQRT3 0.57735026918962576451f
#define INV_SQRT2 0.70710678118654752440f

// ---------------- phase 1: bucket edge ids by destination row ----------------
__global__ void hist_scatter(const int* __restrict__ rows,
                             int* __restrict__ cnt,
                             int* __restrict__ bucket,
                             int* __restrict__ ovf_cnt,
                             int* __restrict__ ovf_list,
                             int E) {
    int e = blockIdx.x * blockDim.x + threadIdx.x;
    if (e >= E) return;
    int r = rows[e];
    int k = atomicAdd(&cnt[r], 1);
    if (k < MAXDEG) {
        bucket[(size_t)r * MAXDEG + k] = e;
    } else {
        int o = atomicAdd(ovf_cnt, 1);
        if (o < OVF_MAX) ovf_list[o] = e;
    }
}

// ---------------- phase 2: persistent waves, one row at a time ----------------
__global__ void tpconv_rows(const float* __restrict__ X,
                            const float* __restrict__ Y,
                            const float* __restrict__ W,
                            const int* __restrict__ cols,
                            const int* __restrict__ cnt,
                            const int* __restrict__ bucket,
                            float* __restrict__ Z,
                            int V) {
    const int nwaves = (gridDim.x * blockDim.x) >> 6;
    const int wave   = (blockIdx.x * blockDim.x + threadIdx.x) >> 6;
    const int lane   = threadIdx.x & 63;
    const int c = lane & 31;   // channel owned by this lane
    const int h = lane >> 5;   // half-wave: h=0 takes even edges, h=1 odd edges

    if (wave >= V) return;

    // prologue: lanes 0..31 hold the row's bucket entries (<= 32)
    int n_cur = cnt[wave];
    int e_cur = (lane < MAXDEG) ? bucket[(size_t)wave * MAXDEG + lane] : 0;

    for (int row = wave; row < V; row += nwaves) {
        const int row_nxt = row + nwaves;
        int n_nxt = 0;
        int e_nxt = 0;
        if (row_nxt < V) {           // prefetch next row while we crunch this one
            n_nxt = cnt[row_nxt];
            if (lane < MAXDEG) e_nxt = bucket[(size_t)row_nxt * MAXDEG + lane];
        }

        int n = n_cur;
        if (n > MAXDEG) n = MAXDEG;
        const int eb = e_cur;

        float acc[11];
#pragma unroll
        for (int j = 0; j < 11; ++j) acc[j] = 0.0f;

        auto body = [&](int e) {
            const float4 y = *reinterpret_cast<const float4*>(Y + (size_t)e * 4);
            const int col = cols[e];

            const float* Xe = X + (size_t)col * (4 * C);
            const float xj0 = Xe[c];
            const float a0  = Xe[C + 3 * c + 0];
            const float a1  = Xe[C + 3 * c + 1];
            const float a2  = Xe[C + 3 * c + 2];

            const float* We = W + (size_t)e * (5 * C);
            const float w0 = We[0 * C + c];
            const float w1 = We[1 * C + c];
            const float w2 = We[2 * C + c];
            const float w3 = We[3 * C + c];
            const float w4 = We[4 * C + c];

            acc[0] += w0 * xj0 * y.x;

            const float t01 = w1 * xj0;
            acc[1] += t01 * y.y;
            acc[2] += t01 * y.z;
            acc[3] += t01 * y.w;

            const float t10 = w2 * y.x;
            acc[4] += t10 * a0;
            acc[5] += t10 * a1;
            acc[6] += t10 * a2;

            acc[7] += w3 * (a0 * y.y + a1 * y.z + a2 * y.w) * INV_SQRT3;

            const float s = w4 * INV_SQRT2;
            acc[8]  += s * (a1 * y.w - a2 * y.z);
            acc[9]  += s * (a2 * y.y - a0 * y.w);
            acc[10] += s * (a0 * y.z - a1 * y.y);
        };

        // Wave-uniform trip count; shfls issue while the wave is CONVERGED.
        // Half-wave h handles indices h, h+2, ... (unroll-by-2): indices
        // 4j+h and 4j+2+h. Max shfl index 4*jmax-1 <= 31 = MAXDEG-1.
        const int jmax = (n + 3) >> 2;
        for (int j = 0; j < jmax; ++j) {
            const int ia = 4 * j + h;
            const int ib = ia + 2;
            const int ea = __shfl(eb, ia);
            const int e2 = __shfl(eb, ib);
            if (ia < n) body(ea);
            if (ib < n) body(e2);
        }

        // combine the two half-wave partial sums (converged here)
#pragma unroll
        for (int j = 0; j < 11; ++j) acc[j] += __shfl_xor(acc[j], 32);

        if (h == 0) {
            float* Zr = Z + (size_t)row * ZCOLS;
            Zr[c]                 = acc[0];
            Zr[C + 3 * c + 0]     = acc[1];
            Zr[C + 3 * c + 1]     = acc[2];
            Zr[C + 3 * c + 2]     = acc[3];
            Zr[4 * C + 3 * c + 0] = acc[4];
            Zr[4 * C + 3 * c + 1] = acc[5];
            Zr[4 * C + 3 * c + 2] = acc[6];
            Zr[7 * C + c]         = acc[7];
            Zr[8 * C + 3 * c + 0] = acc[8];
            Zr[8 * C + 3 * c + 1] = acc[9];
            Zr[8 * C + 3 * c + 2] = acc[10];
        }

        n_cur = n_nxt;
        e_cur = e_nxt;
    }
}

// ---------------- phase 3: rare-overflow fallback (~35 edges) ----------------
__global__ void ovf_apply(const float* __restrict__ X,
                          const float* __restrict__ Y,
                          const float* __restrict__ W,
                          const int* __restrict__ rows,
                          const int* __restrict__ cols,
                          const int* __restrict__ ovf_cnt,
                          const int* __restrict__ ovf_list,
                          float* __restrict__ Z) {
    int no = *ovf_cnt;
    if (no > OVF_MAX) no = OVF_MAX;
    int total = no * C;
    for (int t = blockIdx.x * blockDim.x + threadIdx.x; t < total;
         t += gridDim.x * blockDim.x) {
        const int i = t >> 5, c = t & 31;
        const int e = ovf_list[i];
        const float4 y = *reinterpret_cast<const float4*>(Y + (size_t)e * 4);
        const int row = rows[e];
        const int col = cols[e];
        const float* Xe = X + (size_t)col * (4 * C);
        const float xj0 = Xe[c];
        const float a0  = Xe[C + 3 * c + 0];
        const float a1  = Xe[C + 3 * c + 1];
        const float a2  = Xe[C + 3 * c + 2];
        const float* We = W + (size_t)e * (5 * C);
        const float w0 = We[c], w1 = We[C + c], w2 = We[2 * C + c],
                    w3 = We[3 * C + c], w4 = We[4 * C + c];
        float* Zr = Z + (size_t)row * ZCOLS;
        atomicAdd(&Zr[c], w0 * xj0 * y.x);
        const float t01 = w1 * xj0;
        atomicAdd(&Zr[C + 3 * c + 0], t01 * y.y);
        atomicAdd(&Zr[C + 3 * c + 1], t01 * y.z);
        atomicAdd(&Zr[C + 3 * c + 2], t01 * y.w);
        const float t10 = w2 * y.x;
        atomicAdd(&Zr[4 * C + 3 * c + 0], t10 * a0);
        atomicAdd(&Zr[4 * C + 3 * c + 1], t10 * a1);
        atomicAdd(&Zr[4 * C + 3 * c + 2], t10 * a2);
        atomicAdd(&Zr[7 * C + c], w3 * (a0 * y.y + a1 * y.z + a2 * y.w) * INV_SQRT3);
        const float s = w4 * INV_SQRT2;
        atomicAdd(&Zr[8 * C + 3 * c + 0], s * (a1 * y.w - a2 * y.z));
        atomicAdd(&Zr[8 * C + 3 * c + 1], s * (a2 * y.y - a0 * y.w));
        atomicAdd(&Zr[8 * C + 3 * c + 2], s * (a0 * y.z - a1 * y.y));
    }
}

extern "C" void kernel_launch(void* const* d_in, const int* in_sizes, int n_in,
                              void* d_out, int out_size, void* d_ws, size_t ws_size,
                              hipStream_t stream) {
    const float* X    = (const float*)d_in[0];
    const float* Y    = (const float*)d_in[1];
    const float* W    = (const float*)d_in[2];
    const int*   rows = (const int*)d_in[3];
    const int*   cols = (const int*)d_in[4];
    float*       Z    = (float*)d_out;

    const int E = in_sizes[1] / 4;        // Y is (E, 4)
    const int V = in_sizes[0] / (4 * C);  // X is (V, 4*C)

    // workspace layout: [bucket: V*MAXDEG ints][cnt: V ints][ovf_cnt: 1][ovf_list]
    int* bucket   = (int*)d_ws;
    int* cnt      = bucket + (size_t)V * MAXDEG;
    int* ovf_cnt  = cnt + V;
    int* ovf_list = ovf_cnt + 1;

    // zero counters (cnt + ovf_cnt contiguous)
    hipMemsetAsync(cnt, 0, (size_t)(V + 1) * sizeof(int), stream);

    {
        const int threads = 256;
        const int blocks = (E + threads - 1) / threads;
        hist_scatter<<<blocks, threads, 0, stream>>>(rows, cnt, bucket, ovf_cnt,
                                                     ovf_list, E);
    }
    {
        const int threads = 256;                  // 4 waves/block
        const int blocks = 2048;                  // 8192 persistent waves (full residency)
        tpconv_rows<<<blocks, threads, 0, stream>>>(X, Y, W, cols, cnt, bucket, Z, V);
    }
    {
        ovf_apply<<<64, 256, 0, stream>>>(X, Y, W, rows, cols, ovf_cnt, ovf_list, Z);
    }
}

// Round 9
// 225.309 us; speedup vs baseline: 3.4276x; 1.0399x over previous
//
#include <hip/hip_runtime.h>
#include <hip/hip_bf16.h>

// TensorProductConv, final: revert to the best-measured variant (R2, 223 µs).
// Bucket edges by destination row (no sort needed), then one WAVE per output
// row accumulates in registers and writes each Z element exactly once.
//
// Evidence from R2-R8: this sits at the random-granule memory ceiling
// (~2.8 TB/s effective on a 512 MB random-640B W stream + L3-served X gather);
// ILP depth, occupancy, bucket layout, prefetch, nontemporal hints, and
// dispatch fusion are all neutral-to-negative.
//
// X: (V, 4*C) f32, Y: (E, 4) f32, W: (E, 5*C) f32, rows/cols: (E,) int32.
// Z: (V, 11*C) f32.  C = 32, V = 50000, E = 800000 (avg degree 16).

#define C 32
#define ZCOLS (11 * C)
#define MAXDEG 64          // Poisson(16): P(deg > 64) ~ 1e-18 per row; overflow list backs this up
#define OVF_MAX 65536
#define INV_SQRT3 0.57735026918962576451f
#define INV_SQRT2 0.70710678118654752440f

// ---------------- phase 1: bucket edges by destination row ----------------
__global__ void hist_scatter(const int* __restrict__ rows,
                             int* __restrict__ cnt,
                             int* __restrict__ bucket,
                             int* __restrict__ ovf_cnt,
                             int* __restrict__ ovf_list,
                             int E) {
    int e = blockIdx.x * blockDim.x + threadIdx.x;
    if (e >= E) return;
    int r = rows[e];
    int k = atomicAdd(&cnt[r], 1);
    if (k < MAXDEG) {
        bucket[(size_t)r * MAXDEG + k] = e;
    } else {
        int o = atomicAdd(ovf_cnt, 1);
        if (o < OVF_MAX) ovf_list[o] = e;
    }
}

// ---------------- phase 2: one wave per row, register accumulation ----------------
__global__ void tpconv_rows(const float* __restrict__ X,
                            const float* __restrict__ Y,
                            const float* __restrict__ W,
                            const int* __restrict__ cols,
                            const int* __restrict__ cnt,
                            const int* __restrict__ bucket,
                            float* __restrict__ Z,
                            int V) {
    int wid  = blockIdx.x * (blockDim.x >> 6) + (threadIdx.x >> 6);
    int lane = threadIdx.x & 63;
    if (wid >= V) return;
    const int c = lane & 31;   // channel owned by this lane
    const int h = lane >> 5;   // half-wave: h=0 takes even edges, h=1 odd edges

    int n = cnt[wid];
    if (n > MAXDEG) n = MAXDEG;

    float acc[11];
#pragma unroll
    for (int j = 0; j < 11; ++j) acc[j] = 0.0f;

    const int* bkt = bucket + (size_t)wid * MAXDEG;
    for (int i = h; i < n; i += 2) {
        const int e = bkt[i];
        const float4 y = *reinterpret_cast<const float4*>(Y + (size_t)e * 4);
        const int col = cols[e];

        const float* Xe = X + (size_t)col * (4 * C);
        const float xj0 = Xe[c];
        const float a0  = Xe[C + 3 * c + 0];
        const float a1  = Xe[C + 3 * c + 1];
        const float a2  = Xe[C + 3 * c + 2];

        const float* We = W + (size_t)e * (5 * C);
        const float w0 = We[0 * C + c];
        const float w1 = We[1 * C + c];
        const float w2 = We[2 * C + c];
        const float w3 = We[3 * C + c];
        const float w4 = We[4 * C + c];

        acc[0] += w0 * xj0 * y.x;

        const float t01 = w1 * xj0;
        acc[1] += t01 * y.y;
        acc[2] += t01 * y.z;
        acc[3] += t01 * y.w;

        const float t10 = w2 * y.x;
        acc[4] += t10 * a0;
        acc[5] += t10 * a1;
        acc[6] += t10 * a2;

        acc[7] += w3 * (a0 * y.y + a1 * y.z + a2 * y.w) * INV_SQRT3;

        const float s = w4 * INV_SQRT2;
        acc[8]  += s * (a1 * y.w - a2 * y.z);
        acc[9]  += s * (a2 * y.y - a0 * y.w);
        acc[10] += s * (a0 * y.z - a1 * y.y);
    }

    // combine the two half-wave partial sums
#pragma unroll
    for (int j = 0; j < 11; ++j) acc[j] += __shfl_xor(acc[j], 32);

    if (h == 0) {
        float* Zr = Z + (size_t)wid * ZCOLS;
        Zr[c]               = acc[0];
        Zr[C + 3 * c + 0]   = acc[1];
        Zr[C + 3 * c + 1]   = acc[2];
        Zr[C + 3 * c + 2]   = acc[3];
        Zr[4 * C + 3 * c + 0] = acc[4];
        Zr[4 * C + 3 * c + 1] = acc[5];
        Zr[4 * C + 3 * c + 2] = acc[6];
        Zr[7 * C + c]       = acc[7];
        Zr[8 * C + 3 * c + 0] = acc[8];
        Zr[8 * C + 3 * c + 1] = acc[9];
        Zr[8 * C + 3 * c + 2] = acc[10];
    }
}

// ---------------- phase 3: rare-overflow fallback (normally 0 edges) ----------------
__global__ void ovf_apply(const float* __restrict__ X,
                          const float* __restrict__ Y,
                          const float* __restrict__ W,
                          const int* __restrict__ rows,
                          const int* __restrict__ cols,
                          const int* __restrict__ ovf_cnt,
                          const int* __restrict__ ovf_list,
                          float* __restrict__ Z) {
    int no = *ovf_cnt;
    if (no > OVF_MAX) no = OVF_MAX;
    int total = no * C;
    for (int t = blockIdx.x * blockDim.x + threadIdx.x; t < total;
         t += gridDim.x * blockDim.x) {
        const int i = t >> 5, c = t & 31;
        const int e = ovf_list[i];
        const float4 y = *reinterpret_cast<const float4*>(Y + (size_t)e * 4);
        const int row = rows[e];
        const int col = cols[e];
        const float* Xe = X + (size_t)col * (4 * C);
        const float xj0 = Xe[c];
        const float a0  = Xe[C + 3 * c + 0];
        const float a1  = Xe[C + 3 * c + 1];
        const float a2  = Xe[C + 3 * c + 2];
        const float* We = W + (size_t)e * (5 * C);
        const float w0 = We[c], w1 = We[C + c], w2 = We[2 * C + c],
                    w3 = We[3 * C + c], w4 = We[4 * C + c];
        float* Zr = Z + (size_t)row * ZCOLS;
        atomicAdd(&Zr[c], w0 * xj0 * y.x);
        const float t01 = w1 * xj0;
        atomicAdd(&Zr[C + 3 * c + 0], t01 * y.y);
        atomicAdd(&Zr[C + 3 * c + 1], t01 * y.z);
        atomicAdd(&Zr[C + 3 * c + 2], t01 * y.w);
        const float t10 = w2 * y.x;
        atomicAdd(&Zr[4 * C + 3 * c + 0], t10 * a0);
        atomicAdd(&Zr[4 * C + 3 * c + 1], t10 * a1);
        atomicAdd(&Zr[4 * C + 3 * c + 2], t10 * a2);
        atomicAdd(&Zr[7 * C + c], w3 * (a0 * y.y + a1 * y.z + a2 * y.w) * INV_SQRT3);
        const float s = w4 * INV_SQRT2;
        atomicAdd(&Zr[8 * C + 3 * c + 0], s * (a1 * y.w - a2 * y.z));
        atomicAdd(&Zr[8 * C + 3 * c + 1], s * (a2 * y.y - a0 * y.w));
        atomicAdd(&Zr[8 * C + 3 * c + 2], s * (a0 * y.z - a1 * y.y));
    }
}

extern "C" void kernel_launch(void* const* d_in, const int* in_sizes, int n_in,
                              void* d_out, int out_size, void* d_ws, size_t ws_size,
                              hipStream_t stream) {
    const float* X    = (const float*)d_in[0];
    const float* Y    = (const float*)d_in[1];
    const float* W    = (const float*)d_in[2];
    const int*   rows = (const int*)d_in[3];
    const int*   cols = (const int*)d_in[4];
    float*       Z    = (float*)d_out;

    const int E = in_sizes[1] / 4;        // Y is (E, 4)
    const int V = in_sizes[0] / (4 * C);  // X is (V, 4*C)

    // workspace layout: [cnt: V][ovf_cnt: 1][ovf_list: OVF_MAX][bucket: V*MAXDEG]
    int* cnt      = (int*)d_ws;
    int* ovf_cnt  = cnt + V;
    int* ovf_list = ovf_cnt + 1;
    int* bucket   = ovf_list + OVF_MAX;

    // zero counters (cnt + ovf_cnt contiguous)
    hipMemsetAsync(cnt, 0, (size_t)(V + 1) * sizeof(int), stream);

    {
        const int threads = 256;
        const int blocks = (E + threads - 1) / threads;
        hist_scatter<<<blocks, threads, 0, stream>>>(rows, cnt, bucket, ovf_cnt,
                                                     ovf_list, E);
    }
    {
        const int threads = 256;                  // 4 waves/block
        const int wavesPerBlock = threads / 64;
        const int blocks = (V + wavesPerBlock - 1) / wavesPerBlock;
        tpconv_rows<<<blocks, threads, 0, stream>>>(X, Y, W, cols, cnt, bucket, Z, V);
    }
    {
        ovf_apply<<<64, 256, 0, stream>>>(X, Y, W, rows, cols, ovf_cnt, ovf_list, Z);
    }
}